// Round 1
// baseline (300.542 us; speedup 1.0000x reference)
//
#include <hip/hip_runtime.h>
#include <hip/hip_bf16.h>

#define S_LEN  2048
#define DHEAD  64
#define NHEADS 32
#define NBATCH 4
#define MASKV  -4294967296.0f   // fp32 value of -2^32+1 (rounds to -2^32)

typedef __attribute__((ext_vector_type(4))) float  f4;
typedef __attribute__((ext_vector_type(8))) short  bh8;   // 8 bf16 in 4 VGPRs

static __device__ __forceinline__ unsigned short f2b(float f){
    // float -> bf16, round-to-nearest-even (inputs are finite)
    unsigned int x = __builtin_bit_cast(unsigned int, f);
    x += 0x7FFFu + ((x >> 16) & 1u);
    return (unsigned short)(x >> 16);
}

// Swizzled LDS index (in 16-bit elements) for a row-major [rows][64] bf16 tile.
// 128B rows -> XOR row bits into byte-bit4 to kill the 16-way ds_read_b128 conflict (G4).
static __device__ __forceinline__ int swzi(int row, int colByte){
    return ((row << 7) + (colByte ^ ((row & 7) << 4))) >> 1;
}

__global__ __launch_bounds__(256)
void attn_main(const float* __restrict__ Q, const float* __restrict__ K,
               const float* __restrict__ V, const int* __restrict__ M,
               float* __restrict__ Out)
{
    __shared__ short Kt[64 * 64];      // [key][d]  bf16, swizzled
    __shared__ short Vt[64 * 64];      // [d][key]  bf16, swizzled (transposed V)
    __shared__ short Pl[4 * 16 * 64];  // per-wave P [q16][key64] bf16, swizzled
    __shared__ float maskf[64];

    const int tid  = threadIdx.x;
    const int wave = tid >> 6;
    const int lane = tid & 63;
    const int g    = lane >> 4;   // lane group 0..3
    const int c    = lane & 15;   // lane col   0..15

    const int qt   = blockIdx.x & 31;   // q-tile (fastest -> causal load balance)
    const int head = blockIdx.x >> 5;
    const int b    = head & (NBATCH - 1);   // batch = head % 4 (mask tiling)

    const size_t headOff = (size_t)head * S_LEN * DHEAD;

    // ---- Q fragments, MFMA A layout: row = lane&15, k = (lane>>4)*8 + j ----
    bh8 aQ[2];
    {
        const float* qp = Q + headOff + (size_t)(qt*64 + wave*16 + c) * DHEAD;
        #pragma unroll
        for (int h = 0; h < 2; ++h){
            f4 f0 = *(const f4*)(qp + h*32 + g*8);
            f4 f1 = *(const f4*)(qp + h*32 + g*8 + 4);
            bh8 a;
            #pragma unroll
            for (int i = 0; i < 4; ++i){
                a[i]   = (short)f2b(f0[i]);
                a[i+4] = (short)f2b(f1[i]);
            }
            aQ[h] = a;
        }
    }

    f4    accO[4] = {};                                        // O C-frags: 4 d-tiles
    float mrow[4] = {-INFINITY, -INFINITY, -INFINITY, -INFINITY};
    float lrow[4] = {0.f, 0.f, 0.f, 0.f};
    const int qbase = qt*64 + wave*16 + 4*g;   // C row = 4g + r

    for (int t = 0; t <= qt; ++t){
        const int kv0 = t * 64;
        __syncthreads();   // prior iteration's LDS reads complete
        // ---- stage K (row-major) and V (transposed), both swizzled ----
        {
            const int r   = tid >> 2;          // key row 0..63
            const int seg = (tid & 3) * 16;    // 16-float segment
            const float* kp = K + headOff + (size_t)(kv0 + r) * DHEAD + seg;
            f4 k0 = *(const f4*)(kp);
            f4 k1 = *(const f4*)(kp + 4);
            f4 k2 = *(const f4*)(kp + 8);
            f4 k3 = *(const f4*)(kp + 12);
            bh8 w0, w1;
            #pragma unroll
            for (int i = 0; i < 4; ++i){
                w0[i]   = (short)f2b(k0[i]);
                w0[i+4] = (short)f2b(k1[i]);
                w1[i]   = (short)f2b(k2[i]);
                w1[i+4] = (short)f2b(k3[i]);
            }
            *(bh8*)&Kt[swzi(r, seg*2     )] = w0;
            *(bh8*)&Kt[swzi(r, seg*2 + 16)] = w1;

            const float* vp = V + headOff + (size_t)(kv0 + r) * DHEAD + seg;
            f4 v0 = *(const f4*)(vp);
            f4 v1 = *(const f4*)(vp + 4);
            f4 v2 = *(const f4*)(vp + 8);
            f4 v3 = *(const f4*)(vp + 12);
            float vv[16];
            *(f4*)&vv[0]  = v0; *(f4*)&vv[4]  = v1;
            *(f4*)&vv[8]  = v2; *(f4*)&vv[12] = v3;
            #pragma unroll
            for (int i = 0; i < 16; ++i)
                Vt[swzi(seg + i, r*2)] = (short)f2b(vv[i]);   // Vt[d][key]

            if (tid < 64)
                maskf[tid] = (float)M[(size_t)b * S_LEN + kv0 + tid];
        }
        __syncthreads();

        // ---- S = Q K^T : 4 key-tiles x 2 k-steps of mfma 16x16x32 ----
        f4 sc[4];
        #pragma unroll
        for (int t16 = 0; t16 < 4; ++t16){
            const int krow = t16*16 + c;   // B-frag: col = key = lane&15
            bh8 b0 = *(const bh8*)&Kt[swzi(krow, g*16)];
            bh8 b1 = *(const bh8*)&Kt[swzi(krow, 64 + g*16)];
            f4 acc = {};
            acc = __builtin_amdgcn_mfma_f32_16x16x32_bf16(aQ[0], b0, acc, 0, 0, 0);
            acc = __builtin_amdgcn_mfma_f32_16x16x32_bf16(aQ[1], b1, acc, 0, 0, 0);
            sc[t16] = acc;
        }
        // ---- scale + key-padding + causal masks (exactly -2^32, fp32 ref semantics) ----
        #pragma unroll
        for (int t16 = 0; t16 < 4; ++t16){
            const int key = kv0 + t16*16 + c;
            const float km = maskf[t16*16 + c];
            #pragma unroll
            for (int r = 0; r < 4; ++r){
                float s = sc[t16][r] * 0.125f;
                s = (km != 0.f || key > qbase + r) ? MASKV : s;
                sc[t16][r] = s;
            }
        }
        // ---- online softmax (rows live on 16 lanes: xor 1,2,4,8 reduce) ----
        float pm[4], al[4];
        #pragma unroll
        for (int r = 0; r < 4; ++r)
            pm[r] = fmaxf(fmaxf(sc[0][r], sc[1][r]), fmaxf(sc[2][r], sc[3][r]));
        #pragma unroll
        for (int r = 0; r < 4; ++r)
            #pragma unroll
            for (int mk = 1; mk < 16; mk <<= 1)
                pm[r] = fmaxf(pm[r], __shfl_xor(pm[r], mk, 64));
        #pragma unroll
        for (int r = 0; r < 4; ++r){
            float mn = fmaxf(mrow[r], pm[r]);   // mn >= MASKV (finite): exp args <= 0
            al[r] = __expf(mrow[r] - mn);
            mrow[r] = mn;
        }
        float ls[4] = {0.f, 0.f, 0.f, 0.f};
        #pragma unroll
        for (int t16 = 0; t16 < 4; ++t16)
            #pragma unroll
            for (int r = 0; r < 4; ++r){
                float p = __expf(sc[t16][r] - mrow[r]);
                sc[t16][r] = p;
                ls[r] += p;
            }
        #pragma unroll
        for (int r = 0; r < 4; ++r){
            #pragma unroll
            for (int mk = 1; mk < 16; mk <<= 1)
                ls[r] += __shfl_xor(ls[r], mk, 64);
            lrow[r] = lrow[r] * al[r] + ls[r];
        }
        // ---- P (C-layout) -> LDS so PV can read it in A-layout ----
        short* Pw = &Pl[wave * 1024];
        #pragma unroll
        for (int t16 = 0; t16 < 4; ++t16)
            #pragma unroll
            for (int r = 0; r < 4; ++r)
                Pw[swzi(4*g + r, (t16*16 + c) * 2)] = (short)f2b(sc[t16][r]);
        asm volatile("s_waitcnt lgkmcnt(0)" ::: "memory");   // per-wave buffer: no barrier
        // ---- rescale O, then O += P V ----
        #pragma unroll
        for (int dt = 0; dt < 4; ++dt)
            #pragma unroll
            for (int r = 0; r < 4; ++r)
                accO[dt][r] *= al[r];
        bh8 pa0 = *(const bh8*)&Pw[swzi(c, g*16)];        // A: row=q=lane&15, k=key
        bh8 pa1 = *(const bh8*)&Pw[swzi(c, 64 + g*16)];
        #pragma unroll
        for (int dt = 0; dt < 4; ++dt){
            const int vr = dt*16 + c;                     // B: col=d=lane&15, k=key
            bh8 v0 = *(const bh8*)&Vt[swzi(vr, g*16)];
            bh8 v1 = *(const bh8*)&Vt[swzi(vr, 64 + g*16)];
            accO[dt] = __builtin_amdgcn_mfma_f32_16x16x32_bf16(pa0, v0, accO[dt], 0, 0, 0);
            accO[dt] = __builtin_amdgcn_mfma_f32_16x16x32_bf16(pa1, v1, accO[dt], 0, 0, 0);
        }
    }

    // ---- epilogue: O / l ----
    #pragma unroll
    for (int r = 0; r < 4; ++r){
        const float inv = 1.0f / lrow[r];
        float* op = Out + headOff + (size_t)(qbase + r) * DHEAD;
        #pragma unroll
        for (int dt = 0; dt < 4; ++dt)
            op[dt*16 + c] = accO[dt][r] * inv;
    }
}

// Rows q < q* (q* = first unmasked key of the batch) have ALL visible keys masked.
// In fp32, score+MASK_NUM == MASK_NUM == causal fill exactly, so the reference
// softmax is uniform over all 2048 keys -> output = column-mean of V.
__global__ __launch_bounds__(256)
void attn_fixup(const float* __restrict__ V, const int* __restrict__ M,
                float* __restrict__ Out)
{
    __shared__ int qstar;
    __shared__ float colsum[4][64];
    const int head = blockIdx.x;
    const int b = head & (NBATCH - 1);
    if (threadIdx.x == 0){
        int q = 0;
        while (q < S_LEN && M[(size_t)b * S_LEN + q] != 0) ++q;
        qstar = q;
    }
    __syncthreads();
    const int qs = qstar;
    if (qs == 0) return;   // uniform across block: safe
    const int col  = threadIdx.x & 63;
    const int part = threadIdx.x >> 6;
    float s = 0.f;
    for (int k = part; k < S_LEN; k += 4)
        s += V[((size_t)head * S_LEN + k) * DHEAD + col];
    colsum[part][col] = s;
    __syncthreads();
    if (threadIdx.x < 64){
        const float mean = (colsum[0][col] + colsum[1][col] +
                            colsum[2][col] + colsum[3][col]) * (1.0f / S_LEN);
        for (int q = 0; q < qs; ++q)
            Out[((size_t)head * S_LEN + q) * DHEAD + col] = mean;
    }
}

extern "C" void kernel_launch(void* const* d_in, const int* in_sizes, int n_in,
                              void* d_out, int out_size, void* d_ws, size_t ws_size,
                              hipStream_t stream)
{
    const float* Q = (const float*)d_in[0];
    const float* K = (const float*)d_in[1];
    const float* V = (const float*)d_in[2];
    const int*   M = (const int*)d_in[3];
    float* Out = (float*)d_out;
    attn_main <<<dim3(NHEADS * (S_LEN / 64)), dim3(256), 0, stream>>>(Q, K, V, M, Out);
    attn_fixup<<<dim3(NHEADS),                dim3(256), 0, stream>>>(V, M, Out);
}

// Round 2
// 282.006 us; speedup vs baseline: 1.0657x; 1.0657x over previous
//
#include <hip/hip_runtime.h>
#include <hip/hip_bf16.h>

#define S_LEN  2048
#define DHEAD  64
#define NHEADS 32
#define NBATCH 4
#define MASKV  -4294967296.0f   // fp32 value of -2^32+1 (rounds to -2^32)

typedef __attribute__((ext_vector_type(4))) float  f4;
typedef __attribute__((ext_vector_type(8))) short  bh8;   // 8 bf16 in 4 VGPRs
typedef unsigned short ushort_t;

static __device__ __forceinline__ unsigned short f2b(float f){
    // float -> bf16, round-to-nearest-even (inputs are finite)
    unsigned int x = __builtin_bit_cast(unsigned int, f);
    x += 0x7FFFu + ((x >> 16) & 1u);
    return (unsigned short)(x >> 16);
}

// Swizzled LDS index (in 16-bit elements) for a row-major [rows][64] bf16 tile.
static __device__ __forceinline__ int swzi(int row, int colByte){
    return ((row << 7) + (colByte ^ ((row & 7) << 4))) >> 1;
}

// ---------------- prepass: K fp32 -> bf16 (same layout) ----------------
__global__ __launch_bounds__(256)
void conv_bf16(const float* __restrict__ in, ushort_t* __restrict__ out, int n8){
    int i = blockIdx.x * 256 + threadIdx.x;
    if (i >= n8) return;
    const f4* p = (const f4*)(in + (size_t)i * 8);
    f4 a = p[0], b = p[1];
    bh8 w;
    #pragma unroll
    for (int k = 0; k < 4; ++k){ w[k] = (short)f2b(a[k]); w[k+4] = (short)f2b(b[k]); }
    *(bh8*)(out + (size_t)i * 8) = w;
}

// ---------------- prepass: V fp32 [H][S][64] -> bf16 transposed [H][64][S] ----------------
__global__ __launch_bounds__(256)
void transpose_v(const float* __restrict__ V, ushort_t* __restrict__ Vt){
    __shared__ short T[64][72];
    const int head = blockIdx.x >> 5;
    const int kv0  = (blockIdx.x & 31) * 64;
    {
        const int r = threadIdx.x >> 2;
        const int s = (threadIdx.x & 3) * 16;
        const float* vp = V + ((size_t)head * S_LEN + kv0 + r) * DHEAD + s;
        f4 v0 = *(const f4*)(vp);
        f4 v1 = *(const f4*)(vp + 4);
        f4 v2 = *(const f4*)(vp + 8);
        f4 v3 = *(const f4*)(vp + 12);
        float vv[16];
        *(f4*)&vv[0] = v0; *(f4*)&vv[4] = v1; *(f4*)&vv[8] = v2; *(f4*)&vv[12] = v3;
        #pragma unroll
        for (int i = 0; i < 16; ++i) T[r][s + i] = (short)f2b(vv[i]);
    }
    __syncthreads();
    {
        const int d  = threadIdx.x >> 2;
        const int k0 = (threadIdx.x & 3) * 16;
        bh8 w0, w1;
        #pragma unroll
        for (int i = 0; i < 8; ++i){ w0[i] = T[k0 + i][d]; w1[i] = T[k0 + 8 + i][d]; }
        ushort_t* op = Vt + ((size_t)head * DHEAD + d) * S_LEN + kv0 + k0;
        *(bh8*)op       = w0;
        *(bh8*)(op + 8) = w1;
    }
}

// ---------------- main attention: 1 wave per block, 16 q-rows, no barriers ----------------
__global__ __launch_bounds__(64)
void attn_main(const float* __restrict__ Q, const ushort_t* __restrict__ Kb,
               const ushort_t* __restrict__ Vt, const int* __restrict__ M,
               float* __restrict__ Out)
{
    __shared__ short Pl[16 * 64];   // per-wave P [q16][key64] bf16, swizzled (2 KB)

    const int lane = threadIdx.x;
    const int g    = lane >> 4;   // lane group 0..3
    const int c    = lane & 15;   // lane col   0..15

    const int head = blockIdx.x & 31;
    const int j    = 127 - (blockIdx.x >> 5);   // 16-row q-chunk, heaviest first
    const int b    = head & (NBATCH - 1);

    const size_t hoff = (size_t)head * S_LEN * DHEAD;
    const int qbase = j * 16 + 4 * g;           // C row = 4g + r

    // Q A-frags (fp32 -> bf16 once): row = c, k(d) = h*32 + g*8 + i
    bh8 aQ[2];
    {
        const float* qp = Q + hoff + (size_t)(j * 16 + c) * DHEAD;
        #pragma unroll
        for (int h = 0; h < 2; ++h){
            f4 f0 = *(const f4*)(qp + h * 32 + g * 8);
            f4 f1 = *(const f4*)(qp + h * 32 + g * 8 + 4);
            bh8 a;
            #pragma unroll
            for (int i = 0; i < 4; ++i){ a[i] = (short)f2b(f0[i]); a[i+4] = (short)f2b(f1[i]); }
            aQ[h] = a;
        }
    }

    f4    accO[4] = {};
    float mrow[4] = {-INFINITY, -INFINITY, -INFINITY, -INFINITY};
    float lrow[4] = {0.f, 0.f, 0.f, 0.f};

    const int nt = (j >> 2) + 1;   // KV tiles of 64 needed for rows [16j,16j+16)

    for (int t = 0; t < nt; ++t){
        const int kv0 = t * 64;

        // ---- S = Q K^T : B-frags straight from global bf16 (L2-hot) ----
        f4 sc[4];
        #pragma unroll
        for (int t16 = 0; t16 < 4; ++t16){
            const ushort_t* kp = Kb + hoff + (size_t)(kv0 + t16 * 16 + c) * DHEAD + g * 8;
            bh8 k0 = *(const bh8*)(kp);
            bh8 k1 = *(const bh8*)(kp + 32);
            f4 acc = {};
            __builtin_amdgcn_s_setprio(1);
            acc = __builtin_amdgcn_mfma_f32_16x16x32_bf16(aQ[0], k0, acc, 0, 0, 0);
            acc = __builtin_amdgcn_mfma_f32_16x16x32_bf16(aQ[1], k1, acc, 0, 0, 0);
            __builtin_amdgcn_s_setprio(0);
            sc[t16] = acc;
        }

        // ---- scale + key-padding + causal (exact -2^32 = fp32 ref semantics) ----
        #pragma unroll
        for (int t16 = 0; t16 < 4; ++t16){
            const int key = kv0 + t16 * 16 + c;
            const int km  = M[(size_t)b * S_LEN + key];
            #pragma unroll
            for (int r = 0; r < 4; ++r){
                float s = sc[t16][r] * 0.125f;
                s = (km != 0 || key > qbase + r) ? MASKV : s;
                sc[t16][r] = s;
            }
        }

        // ---- online softmax (row lives on 16 lanes, xor 1/2/4/8 reduce) ----
        float pm[4], al[4];
        #pragma unroll
        for (int r = 0; r < 4; ++r)
            pm[r] = fmaxf(fmaxf(sc[0][r], sc[1][r]), fmaxf(sc[2][r], sc[3][r]));
        #pragma unroll
        for (int r = 0; r < 4; ++r)
            #pragma unroll
            for (int mk = 1; mk < 16; mk <<= 1)
                pm[r] = fmaxf(pm[r], __shfl_xor(pm[r], mk, 64));
        #pragma unroll
        for (int r = 0; r < 4; ++r){
            float mn = fmaxf(mrow[r], pm[r]);
            al[r] = __expf(mrow[r] - mn);
            mrow[r] = mn;
        }
        float ls[4] = {0.f, 0.f, 0.f, 0.f};
        #pragma unroll
        for (int t16 = 0; t16 < 4; ++t16)
            #pragma unroll
            for (int r = 0; r < 4; ++r){
                float p = __expf(sc[t16][r] - mrow[r]);
                sc[t16][r] = p;
                ls[r] += p;
            }
        #pragma unroll
        for (int r = 0; r < 4; ++r){
            #pragma unroll
            for (int mk = 1; mk < 16; mk <<= 1)
                ls[r] += __shfl_xor(ls[r], mk, 64);
            lrow[r] = lrow[r] * al[r] + ls[r];
        }

        // ---- P (C-layout) -> LDS -> A-layout (per-wave, no barrier) ----
        #pragma unroll
        for (int t16 = 0; t16 < 4; ++t16)
            #pragma unroll
            for (int r = 0; r < 4; ++r)
                Pl[swzi(4 * g + r, (t16 * 16 + c) * 2)] = (short)f2b(sc[t16][r]);
        asm volatile("s_waitcnt lgkmcnt(0)" ::: "memory");
        bh8 pa0 = *(const bh8*)&Pl[swzi(c, g * 16)];
        bh8 pa1 = *(const bh8*)&Pl[swzi(c, 64 + g * 16)];

        // ---- rescale O, then O += P V (V^T B-frags straight from global) ----
        #pragma unroll
        for (int dt = 0; dt < 4; ++dt)
            #pragma unroll
            for (int r = 0; r < 4; ++r)
                accO[dt][r] *= al[r];
        #pragma unroll
        for (int dt = 0; dt < 4; ++dt){
            const ushort_t* vp = Vt + ((size_t)head * DHEAD + dt * 16 + c) * S_LEN + kv0 + g * 8;
            bh8 v0 = *(const bh8*)(vp);
            bh8 v1 = *(const bh8*)(vp + 32);
            __builtin_amdgcn_s_setprio(1);
            accO[dt] = __builtin_amdgcn_mfma_f32_16x16x32_bf16(pa0, v0, accO[dt], 0, 0, 0);
            accO[dt] = __builtin_amdgcn_mfma_f32_16x16x32_bf16(pa1, v1, accO[dt], 0, 0, 0);
            __builtin_amdgcn_s_setprio(0);
        }
    }

    // ---- epilogue: O / l ----
    #pragma unroll
    for (int r = 0; r < 4; ++r){
        const float inv = 1.0f / lrow[r];
        float* op = Out + hoff + (size_t)(qbase + r) * DHEAD;
        #pragma unroll
        for (int dt = 0; dt < 4; ++dt)
            op[dt * 16 + c] = accO[dt][r] * inv;
    }
}

// Rows q < q* (q* = first unmasked key of the batch) have ALL visible keys masked.
// In fp32, score+MASK_NUM == MASK_NUM == causal fill exactly, so the reference
// softmax is uniform over all 2048 keys -> output = column-mean of V.
__global__ __launch_bounds__(256)
void attn_fixup(const float* __restrict__ V, const int* __restrict__ M,
                float* __restrict__ Out)
{
    __shared__ int qstar;
    __shared__ float colsum[4][64];
    const int head = blockIdx.x;
    const int b = head & (NBATCH - 1);
    if (threadIdx.x == 0){
        int q = 0;
        while (q < S_LEN && M[(size_t)b * S_LEN + q] != 0) ++q;
        qstar = q;
    }
    __syncthreads();
    const int qs = qstar;
    if (qs == 0) return;
    const int col  = threadIdx.x & 63;
    const int part = threadIdx.x >> 6;
    float s = 0.f;
    for (int k = part; k < S_LEN; k += 4)
        s += V[((size_t)head * S_LEN + k) * DHEAD + col];
    colsum[part][col] = s;
    __syncthreads();
    if (threadIdx.x < 64){
        const float mean = (colsum[0][col] + colsum[1][col] +
                            colsum[2][col] + colsum[3][col]) * (1.0f / S_LEN);
        for (int q = 0; q < qs; ++q)
            Out[((size_t)head * S_LEN + q) * DHEAD + col] = mean;
    }
}

extern "C" void kernel_launch(void* const* d_in, const int* in_sizes, int n_in,
                              void* d_out, int out_size, void* d_ws, size_t ws_size,
                              hipStream_t stream)
{
    const float* Q = (const float*)d_in[0];
    const float* K = (const float*)d_in[1];
    const float* V = (const float*)d_in[2];
    const int*   M = (const int*)d_in[3];
    float* Out = (float*)d_out;

    ushort_t* Kb = (ushort_t*)d_ws;                                   // 8.39 MB
    ushort_t* Vt = Kb + (size_t)NHEADS * S_LEN * DHEAD;               // 8.39 MB

    const int n8 = NHEADS * S_LEN * DHEAD / 8;                        // 524288
    conv_bf16  <<<dim3(n8 / 256),        dim3(256), 0, stream>>>(K, Kb, n8);
    transpose_v<<<dim3(NHEADS * 32),     dim3(256), 0, stream>>>(V, Vt);
    attn_main  <<<dim3(NHEADS * 128),    dim3(64),  0, stream>>>(Q, Kb, Vt, M, Out);
    attn_fixup <<<dim3(NHEADS),          dim3(256), 0, stream>>>(V, M, Out);
}

// Round 4
// 236.534 us; speedup vs baseline: 1.2706x; 1.1922x over previous
//
#include <hip/hip_runtime.h>
#include <hip/hip_bf16.h>

#define S_LEN  2048
#define DHEAD  64
#define NHEADS 32
#define NBATCH 4
#define LOG2E  1.44269504f
// fp32(-2^32 * log2e): the one "masked" score in log2 domain. |real scores| << ulp here,
// so score+mask collapses to exactly CMASK, preserving the reference's fp32 semantics
// (all-visible-masked rows become uniform; fixup kernel finishes those).
#define CMASK  (-4294967296.0f * 1.44269504f)

typedef __attribute__((ext_vector_type(4)))  float f4;
typedef __attribute__((ext_vector_type(8)))  short bh8;    // 8 bf16
typedef __attribute__((ext_vector_type(16))) float f16x;   // 32x32 MFMA C/D
typedef __attribute__((ext_vector_type(4)))  int   i4;
typedef __attribute__((ext_vector_type(2)))  int   i2;
typedef unsigned short ushort_t;

static __device__ __forceinline__ unsigned short f2b(float f){
    unsigned int x = __builtin_bit_cast(unsigned int, f);
    x += 0x7FFFu + ((x >> 16) & 1u);
    return (unsigned short)(x >> 16);
}
static __device__ __forceinline__ int pack2(float a, float b){
    return (int)((unsigned)f2b(a) | ((unsigned)f2b(b) << 16));
}

// ---- prep: blocks [0,2048) = K->bf16 ; [2048,3072) = V->bf16 transposed ----
__global__ __launch_bounds__(256)
void prep(const float* __restrict__ K, const float* __restrict__ V,
          ushort_t* __restrict__ Kb, ushort_t* __restrict__ Vt)
{
    const int bid = blockIdx.x;
    const int tid = threadIdx.x;
    if (bid < 2048){                       // K conversion: 8 floats/thread
        const int i = bid * 256 + tid;
        const f4* p = (const f4*)(K + (size_t)i * 8);
        f4 a = p[0], b = p[1];
        bh8 w;
        #pragma unroll
        for (int k = 0; k < 4; ++k){ w[k] = (short)f2b(a[k]); w[k+4] = (short)f2b(b[k]); }
        *(bh8*)(Kb + (size_t)i * 8) = w;
    } else {                               // V transpose -> Vt[h][d][s] bf16
        __shared__ short T[64][72];
        const int r2 = bid - 2048;
        const int head = r2 >> 5;
        const int kv0  = (r2 & 31) * 64;
        {
            const int r = tid >> 2;
            const int s = (tid & 3) * 16;
            const float* vp = V + ((size_t)head * S_LEN + kv0 + r) * DHEAD + s;
            f4 v0 = *(const f4*)(vp);
            f4 v1 = *(const f4*)(vp + 4);
            f4 v2 = *(const f4*)(vp + 8);
            f4 v3 = *(const f4*)(vp + 12);
            float vv[16];
            *(f4*)&vv[0] = v0; *(f4*)&vv[4] = v1; *(f4*)&vv[8] = v2; *(f4*)&vv[12] = v3;
            #pragma unroll
            for (int i = 0; i < 16; ++i) T[r][s + i] = (short)f2b(vv[i]);
        }
        __syncthreads();
        {
            const int d  = tid >> 2;
            const int k0 = (tid & 3) * 16;
            bh8 w0, w1;
            #pragma unroll
            for (int i = 0; i < 8; ++i){ w0[i] = T[k0 + i][d]; w1[i] = T[k0 + 8 + i][d]; }
            ushort_t* op = Vt + ((size_t)head * DHEAD + d) * S_LEN + kv0 + k0;
            *(bh8*)op       = w0;
            *(bh8*)(op + 8) = w1;
        }
    }
}

// ---- main attention: 4 independent waves/block, 32 q-rows/wave, swapped QK^T ----
__global__ __launch_bounds__(256)
void attn_main(const float* __restrict__ Q, const ushort_t* __restrict__ Kb,
               const ushort_t* __restrict__ Vt, const int* __restrict__ M,
               float* __restrict__ Out)
{
    __shared__ char Pl[4][2048];   // per-wave P buffer: 32 q-rows x 32 keys bf16, swizzled

    const int tid  = threadIdx.x;
    const int wave = tid >> 6;
    const int lane = tid & 63;
    const int lq   = lane & 31;   // q column owned by this lane
    const int hi   = lane >> 5;

    const int bid  = blockIdx.x;
    // heads clustered per XCD (4 heads/XCD -> K+V L2-resident); jq descending (heaviest first)
    const int head = ((bid & 7) << 2) | ((bid >> 3) & 3);
    const int jq   = 63 - (((bid >> 5) << 2) | wave);
    const int b    = head & (NBATCH - 1);
    const int q0   = jq << 5;
    const size_t hoff = (size_t)head * S_LEN * DHEAD;

    char* pw = Pl[wave] + lq * 64;              // this lane's P row (64 bytes)
    const int swzq = (lq ^ (lq >> 2)) & 3;      // 16B-block XOR swizzle per row

    // Q B-frags (col=lane&31=q, k=hi*8+j), scale 0.125*log2e folded in
    bh8 qB[4];
    {
        const float* qp = Q + hoff + (size_t)(q0 + lq) * DHEAD;
        const float qs = 0.125f * LOG2E;
        #pragma unroll
        for (int ks = 0; ks < 4; ++ks){
            f4 f0 = *(const f4*)(qp + ks * 16 + hi * 8);
            f4 f1 = *(const f4*)(qp + ks * 16 + hi * 8 + 4);
            bh8 a;
            #pragma unroll
            for (int i = 0; i < 4; ++i){
                a[i]   = (short)f2b(f0[i] * qs);
                a[i+4] = (short)f2b(f1[i] * qs);
            }
            qB[ks] = a;
        }
    }

    f16x acc0 = {};   // O^T rows d=0..31:  col=q=lq, row d=(reg&3)+8*(reg>>2)+4*hi
    f16x acc1 = {};   // O^T rows d=32..63
    float m = -INFINITY, l = 0.f;

    const ushort_t* kbase = Kb + hoff;
    const ushort_t* vbase = Vt + (size_t)head * DHEAD * S_LEN;
    const int* mrow = M + (size_t)b * S_LEN;
    const int nkt = jq + 1;

    for (int kt = 0; kt < nkt; ++kt){
        const int kv0 = kt << 5;
        // ---- all global loads issued up front ----
        bh8 kf[4], vf0[2], vf1[2];
        i4  mi[4];
        #pragma unroll
        for (int ks = 0; ks < 4; ++ks)
            kf[ks] = *(const bh8*)(kbase + (size_t)(kv0 + lq) * DHEAD + ks * 16 + hi * 8);
        #pragma unroll
        for (int kk = 0; kk < 2; ++kk){
            vf0[kk] = *(const bh8*)(vbase + (size_t)lq        * S_LEN + kv0 + kk * 16 + hi * 8);
            vf1[kk] = *(const bh8*)(vbase + (size_t)(32 + lq) * S_LEN + kv0 + kk * 16 + hi * 8);
        }
        #pragma unroll
        for (int g = 0; g < 4; ++g)
            mi[g] = *(const i4*)(mrow + kv0 + g * 8 + hi * 4);

        // ---- S^T = K Q^T (swapped): lane holds 16 scores of q-row lq ----
        f16x s = {};
        __builtin_amdgcn_s_setprio(1);
        #pragma unroll
        for (int ks = 0; ks < 4; ++ks)
            s = __builtin_amdgcn_mfma_f32_32x32x16_bf16(kf[ks], qB[ks], s, 0, 0, 0);
        __builtin_amdgcn_s_setprio(0);

        // ---- key-padding; causal on diagonal tile. reg g*4+i -> key 8g+4hi+i ----
        #pragma unroll
        for (int g = 0; g < 4; ++g)
            #pragma unroll
            for (int i = 0; i < 4; ++i)
                s[g * 4 + i] = (mi[g][i] != 0) ? CMASK : s[g * 4 + i];
        if (kt == jq){
            const int hb = hi << 2;
            #pragma unroll
            for (int g = 0; g < 4; ++g)
                #pragma unroll
                for (int i = 0; i < 4; ++i)
                    s[g * 4 + i] = (g * 8 + i + hb > lq) ? CMASK : s[g * 4 + i];
        }

        // ---- row max: local tree + shfl_xor across lane halves ----
        float t8[8];
        #pragma unroll
        for (int i = 0; i < 8; ++i) t8[i] = fmaxf(s[i], s[i + 8]);
        #pragma unroll
        for (int i = 0; i < 4; ++i) t8[i] = fmaxf(t8[i], t8[i + 4]);
        float pml = fmaxf(fmaxf(t8[0], t8[1]), fmaxf(t8[2], t8[3]));
        float pm  = fmaxf(pml, __shfl_xor(pml, 32, 64));

        // ---- deferred rescale (log2 units; 2^11 headroom is bf16/f32-safe) ----
        if (!__all(pm <= m + 11.0f)){
            float mn = fmaxf(m, pm);
            float al = __builtin_amdgcn_exp2f(m - mn);
            m = mn;
            l *= al;
            #pragma unroll
            for (int i = 0; i < 16; ++i){ acc0[i] *= al; acc1[i] *= al; }
        }

        // ---- P = exp2(S - m), row sum ----
        #pragma unroll
        for (int i = 0; i < 16; ++i) s[i] = __builtin_amdgcn_exp2f(s[i] - m);
        float u8[8];
        #pragma unroll
        for (int i = 0; i < 8; ++i) u8[i] = s[i] + s[i + 8];
        #pragma unroll
        for (int i = 0; i < 4; ++i) u8[i] = u8[i] + u8[i + 4];
        float lsl = (u8[0] + u8[1]) + (u8[2] + u8[3]);
        l += lsl + __shfl_xor(lsl, 32, 64);

        // ---- P -> LDS (C-layout) -> B-frag (per-wave buffer, no barrier) ----
        // physical 16B block of logical key k: (k>>3) ^ swzq ; reg g*4+i holds key 8g+4hi+i
        #pragma unroll
        for (int g = 0; g < 4; ++g){
            i2 w;
            w[0] = pack2(s[g * 4 + 0], s[g * 4 + 1]);
            w[1] = pack2(s[g * 4 + 2], s[g * 4 + 3]);
            *(i2*)(pw + (((g ^ swzq) << 4) + (hi << 3))) = w;
        }
        asm volatile("s_waitcnt lgkmcnt(0)" ::: "memory");
        __builtin_amdgcn_sched_barrier(0);
        bh8 pa1 = *(const bh8*)(pw + ((hi ^ swzq) << 4));          // keys hi*8+0..7
        bh8 pa2 = *(const bh8*)(pw + (((2 | hi) ^ swzq) << 4));    // keys 16+hi*8+0..7

        // ---- O^T += V^T P^T ----
        __builtin_amdgcn_s_setprio(1);
        acc0 = __builtin_amdgcn_mfma_f32_32x32x16_bf16(vf0[0], pa1, acc0, 0, 0, 0);
        acc0 = __builtin_amdgcn_mfma_f32_32x32x16_bf16(vf0[1], pa2, acc0, 0, 0, 0);
        acc1 = __builtin_amdgcn_mfma_f32_32x32x16_bf16(vf1[0], pa1, acc1, 0, 0, 0);
        acc1 = __builtin_amdgcn_mfma_f32_32x32x16_bf16(vf1[1], pa2, acc1, 0, 0, 0);
        __builtin_amdgcn_s_setprio(0);
    }

    // ---- epilogue: O[q][d] = acc/l ; reg g*4+i -> d = 8g+4hi+i ----
    const float inv = 1.0f / l;
    float* op = Out + hoff + (size_t)(q0 + lq) * DHEAD;
    #pragma unroll
    for (int g = 0; g < 4; ++g){
        f4 o0, o1;
        #pragma unroll
        for (int i = 0; i < 4; ++i){ o0[i] = acc0[g * 4 + i] * inv; o1[i] = acc1[g * 4 + i] * inv; }
        *(f4*)(op + g * 8 + hi * 4)      = o0;
        *(f4*)(op + 32 + g * 8 + hi * 4) = o1;
    }
}

// Rows q < q* (q* = first unmasked key of the batch): reference softmax is uniform over
// ALL 2048 keys -> output = column mean of V. Overwrite those rows. (R2-verified version.)
__global__ __launch_bounds__(256)
void attn_fixup(const float* __restrict__ V, const int* __restrict__ M,
                float* __restrict__ Out)
{
    __shared__ int qstar;
    __shared__ float colsum[4][64];
    const int head = blockIdx.x;
    const int b = head & (NBATCH - 1);
    if (threadIdx.x == 0){
        int q = 0;
        while (q < S_LEN && M[(size_t)b * S_LEN + q] != 0) ++q;
        qstar = q;
    }
    __syncthreads();
    const int qs = qstar;
    if (qs == 0) return;
    const int col  = threadIdx.x & 63;
    const int part = threadIdx.x >> 6;
    float s = 0.f;
    for (int k = part; k < S_LEN; k += 4)
        s += V[((size_t)head * S_LEN + k) * DHEAD + col];
    colsum[part][col] = s;
    __syncthreads();
    if (threadIdx.x < 64){
        const float mean = (colsum[0][col] + colsum[1][col] +
                            colsum[2][col] + colsum[3][col]) * (1.0f / S_LEN);
        for (int q = 0; q < qs; ++q)
            Out[((size_t)head * S_LEN + q) * DHEAD + col] = mean;
    }
}

extern "C" void kernel_launch(void* const* d_in, const int* in_sizes, int n_in,
                              void* d_out, int out_size, void* d_ws, size_t ws_size,
                              hipStream_t stream)
{
    const float* Q = (const float*)d_in[0];
    const float* K = (const float*)d_in[1];
    const float* V = (const float*)d_in[2];
    const int*   M = (const int*)d_in[3];
    float* Out = (float*)d_out;

    ushort_t* Kb = (ushort_t*)d_ws;                      // 8.39 MB
    ushort_t* Vt = Kb + (size_t)NHEADS * S_LEN * DHEAD;  // 8.39 MB  (total = 16 MiB, as R2)

    prep      <<<dim3(3072),   dim3(256), 0, stream>>>(K, V, Kb, Vt);
    attn_main <<<dim3(512),    dim3(256), 0, stream>>>(Q, Kb, Vt, M, Out);
    attn_fixup<<<dim3(NHEADS), dim3(256), 0, stream>>>(V, M, Out);
}

// Round 5
// 116.293 us; speedup vs baseline: 2.5844x; 2.0339x over previous
//
#include <hip/hip_runtime.h>
#include <hip/hip_bf16.h>

#define S_LEN  2048
#define DHEAD  64
#define NHEADS 32
#define NBATCH 4
#define LOG2E  1.44269504f
// fp32(-2^32 * log2e): the one "masked" score in log2 domain. |real scores| << ulp here,
// so score+mask collapses to exactly CMASK, preserving the reference's fp32 semantics
// (all-visible-masked rows become uniform; fixup kernel finishes those).
#define CMASK  (-4294967296.0f * 1.44269504f)

typedef __attribute__((ext_vector_type(4)))  float f4;
typedef __attribute__((ext_vector_type(8)))  short bh8;    // 8 bf16
typedef __attribute__((ext_vector_type(16))) float f16x;   // 32x32 MFMA C/D
typedef __attribute__((ext_vector_type(4)))  int   i4;
typedef __attribute__((ext_vector_type(2)))  int   i2;
typedef unsigned short ushort_t;

static __device__ __forceinline__ unsigned short f2b(float f){
    unsigned int x = __builtin_bit_cast(unsigned int, f);
    x += 0x7FFFu + ((x >> 16) & 1u);
    return (unsigned short)(x >> 16);
}
static __device__ __forceinline__ float b2f(ushort_t u){
    return __builtin_bit_cast(float, ((unsigned)u) << 16);
}
static __device__ __forceinline__ int pack2(float a, float b){
    return (int)((unsigned)f2b(a) | ((unsigned)f2b(b) << 16));
}

// ---- prep: blocks [0,2048) = K->bf16 ; [2048,3072) = V->bf16 transposed + col partials ----
__global__ __launch_bounds__(256)
void prep(const float* __restrict__ K, const float* __restrict__ V,
          ushort_t* __restrict__ Kb, ushort_t* __restrict__ Vt,
          float* __restrict__ colpart)
{
    const int bid = blockIdx.x;
    const int tid = threadIdx.x;
    if (bid < 2048){                       // K conversion: 8 floats/thread
        const int i = bid * 256 + tid;
        const f4* p = (const f4*)(K + (size_t)i * 8);
        f4 a = p[0], b = p[1];
        bh8 w;
        #pragma unroll
        for (int k = 0; k < 4; ++k){ w[k] = (short)f2b(a[k]); w[k+4] = (short)f2b(b[k]); }
        *(bh8*)(Kb + (size_t)i * 8) = w;
    } else {                               // V transpose -> Vt[h][d][s] bf16 (+ column sums)
        __shared__ short T[64][72];
        __shared__ float red[64][4];
        const int r2 = bid - 2048;         // 0..1023 = head*32 + slice
        const int head = r2 >> 5;
        const int kv0  = (r2 & 31) * 64;
        {
            const int r = tid >> 2;
            const int s = (tid & 3) * 16;
            const float* vp = V + ((size_t)head * S_LEN + kv0 + r) * DHEAD + s;
            f4 v0 = *(const f4*)(vp);
            f4 v1 = *(const f4*)(vp + 4);
            f4 v2 = *(const f4*)(vp + 8);
            f4 v3 = *(const f4*)(vp + 12);
            float vv[16];
            *(f4*)&vv[0] = v0; *(f4*)&vv[4] = v1; *(f4*)&vv[8] = v2; *(f4*)&vv[12] = v3;
            #pragma unroll
            for (int i = 0; i < 16; ++i) T[r][s + i] = (short)f2b(vv[i]);
        }
        __syncthreads();
        {
            const int d  = tid >> 2;
            const int k0 = (tid & 3) * 16;
            bh8 w0, w1;
            float s16 = 0.f;
            #pragma unroll
            for (int i = 0; i < 8; ++i){
                w0[i] = T[k0 + i][d];
                w1[i] = T[k0 + 8 + i][d];
                s16 += b2f((ushort_t)w0[i]) + b2f((ushort_t)w1[i]);
            }
            ushort_t* op = Vt + ((size_t)head * DHEAD + d) * S_LEN + kv0 + k0;
            *(bh8*)op       = w0;
            *(bh8*)(op + 8) = w1;
            red[d][tid & 3] = s16;
        }
        __syncthreads();
        if (tid < 64)
            colpart[(size_t)r2 * 64 + tid] =
                red[tid][0] + red[tid][1] + red[tid][2] + red[tid][3];
    }
}

// ---- main attention: 4 independent waves/block, 32 q-rows/wave, swapped QK^T ----
__global__ __launch_bounds__(256)
void attn_main(const float* __restrict__ Q, const ushort_t* __restrict__ Kb,
               const ushort_t* __restrict__ Vt, const int* __restrict__ M,
               float* __restrict__ Out)
{
    __shared__ char Pl[4][2048];   // per-wave P buffer: 32 q-rows x 32 keys bf16, swizzled

    const int tid  = threadIdx.x;
    const int wave = tid >> 6;
    const int lane = tid & 63;
    const int lq   = lane & 31;   // q column owned by this lane
    const int hi   = lane >> 5;

    const int bid  = blockIdx.x;
    // heads clustered per XCD (4 heads/XCD -> K+V L2-resident); jq descending (heaviest first)
    const int head = ((bid & 7) << 2) | ((bid >> 3) & 3);
    const int jq   = 63 - (((bid >> 5) << 2) | wave);
    const int b    = head & (NBATCH - 1);
    const int q0   = jq << 5;
    const size_t hoff = (size_t)head * S_LEN * DHEAD;

    char* pw = Pl[wave] + lq * 64;              // this lane's P row (64 bytes)
    const int swzq = (lq ^ (lq >> 2)) & 3;      // 16B-block XOR swizzle per row

    // Q B-frags (col=lane&31=q, k=hi*8+j), scale 0.125*log2e folded in
    bh8 qB[4];
    {
        const float* qp = Q + hoff + (size_t)(q0 + lq) * DHEAD;
        const float qs = 0.125f * LOG2E;
        #pragma unroll
        for (int ks = 0; ks < 4; ++ks){
            f4 f0 = *(const f4*)(qp + ks * 16 + hi * 8);
            f4 f1 = *(const f4*)(qp + ks * 16 + hi * 8 + 4);
            bh8 a;
            #pragma unroll
            for (int i = 0; i < 4; ++i){
                a[i]   = (short)f2b(f0[i] * qs);
                a[i+4] = (short)f2b(f1[i] * qs);
            }
            qB[ks] = a;
        }
    }

    f16x acc0 = {};   // O^T rows d=0..31:  col=q=lq, row d=(reg&3)+8*(reg>>2)+4*hi
    f16x acc1 = {};   // O^T rows d=32..63
    float m = -INFINITY, l = 0.f;

    const ushort_t* kbase = Kb + hoff;
    const ushort_t* vbase = Vt + (size_t)head * DHEAD * S_LEN;
    const int* mrow = M + (size_t)b * S_LEN;
    const int nkt = jq + 1;

    for (int kt = 0; kt < nkt; ++kt){
        const int kv0 = kt << 5;
        // ---- all global loads issued up front ----
        bh8 kf[4], vf0[2], vf1[2];
        i4  mi[4];
        #pragma unroll
        for (int ks = 0; ks < 4; ++ks)
            kf[ks] = *(const bh8*)(kbase + (size_t)(kv0 + lq) * DHEAD + ks * 16 + hi * 8);
        #pragma unroll
        for (int kk = 0; kk < 2; ++kk){
            vf0[kk] = *(const bh8*)(vbase + (size_t)lq        * S_LEN + kv0 + kk * 16 + hi * 8);
            vf1[kk] = *(const bh8*)(vbase + (size_t)(32 + lq) * S_LEN + kv0 + kk * 16 + hi * 8);
        }
        #pragma unroll
        for (int g = 0; g < 4; ++g)
            mi[g] = *(const i4*)(mrow + kv0 + g * 8 + hi * 4);

        // ---- S^T = K Q^T (swapped): lane holds 16 scores of q-row lq ----
        f16x s = {};
        __builtin_amdgcn_s_setprio(1);
        #pragma unroll
        for (int ks = 0; ks < 4; ++ks)
            s = __builtin_amdgcn_mfma_f32_32x32x16_bf16(kf[ks], qB[ks], s, 0, 0, 0);
        __builtin_amdgcn_s_setprio(0);

        // ---- key-padding; causal on diagonal tile. reg g*4+i -> key 8g+4hi+i ----
        #pragma unroll
        for (int g = 0; g < 4; ++g)
            #pragma unroll
            for (int i = 0; i < 4; ++i)
                s[g * 4 + i] = (mi[g][i] != 0) ? CMASK : s[g * 4 + i];
        if (kt == jq){
            const int hb = hi << 2;
            #pragma unroll
            for (int g = 0; g < 4; ++g)
                #pragma unroll
                for (int i = 0; i < 4; ++i)
                    s[g * 4 + i] = (g * 8 + i + hb > lq) ? CMASK : s[g * 4 + i];
        }

        // ---- row max: local tree + shfl_xor across lane halves ----
        float t8[8];
        #pragma unroll
        for (int i = 0; i < 8; ++i) t8[i] = fmaxf(s[i], s[i + 8]);
        #pragma unroll
        for (int i = 0; i < 4; ++i) t8[i] = fmaxf(t8[i], t8[i + 4]);
        float pml = fmaxf(fmaxf(t8[0], t8[1]), fmaxf(t8[2], t8[3]));
        float pm  = fmaxf(pml, __shfl_xor(pml, 32, 64));

        // ---- deferred rescale (log2 units; 2^11 headroom is bf16/f32-safe) ----
        if (!__all(pm <= m + 11.0f)){
            float mn = fmaxf(m, pm);
            float al = __builtin_amdgcn_exp2f(m - mn);
            m = mn;
            l *= al;
            #pragma unroll
            for (int i = 0; i < 16; ++i){ acc0[i] *= al; acc1[i] *= al; }
        }

        // ---- P = exp2(S - m), row sum ----
        #pragma unroll
        for (int i = 0; i < 16; ++i) s[i] = __builtin_amdgcn_exp2f(s[i] - m);
        float u8[8];
        #pragma unroll
        for (int i = 0; i < 8; ++i) u8[i] = s[i] + s[i + 8];
        #pragma unroll
        for (int i = 0; i < 4; ++i) u8[i] = u8[i] + u8[i + 4];
        float lsl = (u8[0] + u8[1]) + (u8[2] + u8[3]);
        l += lsl + __shfl_xor(lsl, 32, 64);

        // ---- P -> LDS (C-layout) -> B-frag (per-wave buffer, no barrier) ----
        // physical 16B block of logical key k: (k>>3) ^ swzq ; reg g*4+i holds key 8g+4hi+i
        #pragma unroll
        for (int g = 0; g < 4; ++g){
            i2 w;
            w[0] = pack2(s[g * 4 + 0], s[g * 4 + 1]);
            w[1] = pack2(s[g * 4 + 2], s[g * 4 + 3]);
            *(i2*)(pw + (((g ^ swzq) << 4) + (hi << 3))) = w;
        }
        asm volatile("s_waitcnt lgkmcnt(0)" ::: "memory");
        __builtin_amdgcn_sched_barrier(0);
        bh8 pa1 = *(const bh8*)(pw + ((hi ^ swzq) << 4));          // keys hi*8+0..7
        bh8 pa2 = *(const bh8*)(pw + (((2 | hi) ^ swzq) << 4));    // keys 16+hi*8+0..7

        // ---- O^T += V^T P^T ----
        __builtin_amdgcn_s_setprio(1);
        acc0 = __builtin_amdgcn_mfma_f32_32x32x16_bf16(vf0[0], pa1, acc0, 0, 0, 0);
        acc0 = __builtin_amdgcn_mfma_f32_32x32x16_bf16(vf0[1], pa2, acc0, 0, 0, 0);
        acc1 = __builtin_amdgcn_mfma_f32_32x32x16_bf16(vf1[0], pa1, acc1, 0, 0, 0);
        acc1 = __builtin_amdgcn_mfma_f32_32x32x16_bf16(vf1[1], pa2, acc1, 0, 0, 0);
        __builtin_amdgcn_s_setprio(0);
    }

    // ---- epilogue: O[q][d] = acc/l ; reg g*4+i -> d = 8g+4hi+i ----
    const float inv = 1.0f / l;
    float* op = Out + hoff + (size_t)(q0 + lq) * DHEAD;
    #pragma unroll
    for (int g = 0; g < 4; ++g){
        f4 o0, o1;
        #pragma unroll
        for (int i = 0; i < 4; ++i){ o0[i] = acc0[g * 4 + i] * inv; o1[i] = acc1[g * 4 + i] * inv; }
        *(f4*)(op + g * 8 + hi * 4)      = o0;
        *(f4*)(op + 32 + g * 8 + hi * 4) = o1;
    }
}

// Rows q < q* (q* = first unmasked key of the batch): reference softmax is uniform over
// ALL 2048 keys -> output = column mean of V. Reduce prep's 32 partial sums per head.
__global__ __launch_bounds__(256)
void attn_fixup(const float* __restrict__ colpart, const int* __restrict__ M,
                float* __restrict__ Out)
{
    __shared__ float red[4][64];
    __shared__ int qstar;
    const int head = blockIdx.x;
    const int b = head & (NBATCH - 1);
    const int tid = threadIdx.x;
    const int col = tid & 63;
    const int grp = tid >> 6;
    {
        float s = 0.f;
        const float* cp = colpart + ((size_t)head * 32 + grp * 8) * 64 + col;
        #pragma unroll
        for (int j = 0; j < 8; ++j) s += cp[j * 64];
        red[grp][col] = s;
    }
    if (tid == 0){
        int q = 0;
        const int* mp = M + (size_t)b * S_LEN;
        while (q < S_LEN && mp[q]) ++q;
        qstar = q;
    }
    __syncthreads();
    const int qs = qstar;
    if (qs == 0) return;
    const float mean = (red[0][col] + red[1][col] + red[2][col] + red[3][col])
                       * (1.0f / S_LEN);
    for (int q = grp; q < qs; q += 4)
        Out[((size_t)head * S_LEN + q) * DHEAD + col] = mean;
}

extern "C" void kernel_launch(void* const* d_in, const int* in_sizes, int n_in,
                              void* d_out, int out_size, void* d_ws, size_t ws_size,
                              hipStream_t stream)
{
    const float* Q = (const float*)d_in[0];
    const float* K = (const float*)d_in[1];
    const float* V = (const float*)d_in[2];
    const int*   M = (const int*)d_in[3];
    float* Out = (float*)d_out;

    ushort_t* Kb = (ushort_t*)d_ws;                                  // 8.39 MB
    ushort_t* Vt = Kb + (size_t)NHEADS * S_LEN * DHEAD;              // 8.39 MB
    float* colpart = (float*)(Vt + (size_t)NHEADS * S_LEN * DHEAD);  // 256 KB

    prep      <<<dim3(3072),   dim3(256), 0, stream>>>(K, V, Kb, Vt, colpart);
    attn_main <<<dim3(512),    dim3(256), 0, stream>>>(Q, Kb, Vt, M, Out);
    attn_fixup<<<dim3(NHEADS), dim3(256), 0, stream>>>(colpart, M, Out);
}

// Round 6
// 108.876 us; speedup vs baseline: 2.7604x; 1.0681x over previous
//
#include <hip/hip_runtime.h>
#include <hip/hip_bf16.h>

#define S_LEN  2048
#define DHEAD  64
#define NHEADS 32
#define NBATCH 4
#define LOG2E  1.44269504f
// fp32(-2^32 * log2e): the one "masked" score in log2 domain. |real scores| << ulp here,
// so score+mask collapses to exactly CMASK, preserving the reference's fp32 semantics
// (all-visible-masked rows become uniform; fixup kernel finishes those).
#define CMASK  (-4294967296.0f * 1.44269504f)

typedef __attribute__((ext_vector_type(4)))  float f4;
typedef __attribute__((ext_vector_type(8)))  short bh8;    // 8 bf16
typedef __attribute__((ext_vector_type(16))) float f16x;   // 32x32 MFMA C/D
typedef __attribute__((ext_vector_type(4)))  int   i4;
typedef __attribute__((ext_vector_type(2)))  int   i2;
typedef unsigned short ushort_t;

static __device__ __forceinline__ unsigned short f2b(float f){
    unsigned int x = __builtin_bit_cast(unsigned int, f);
    x += 0x7FFFu + ((x >> 16) & 1u);
    return (unsigned short)(x >> 16);
}
static __device__ __forceinline__ float b2f(ushort_t u){
    return __builtin_bit_cast(float, ((unsigned)u) << 16);
}
static __device__ __forceinline__ int pack2(float a, float b){
    return (int)((unsigned)f2b(a) | ((unsigned)f2b(b) << 16));
}

// ---- prep: blocks [0,2048) = K->bf16 ; [2048,3072) = V->bf16 transposed + col partials ----
__global__ __launch_bounds__(256)
void prep(const float* __restrict__ K, const float* __restrict__ V,
          ushort_t* __restrict__ Kb, ushort_t* __restrict__ Vt,
          float* __restrict__ colpart)
{
    const int bid = blockIdx.x;
    const int tid = threadIdx.x;
    if (bid < 2048){                       // K conversion: 8 floats/thread
        const int i = bid * 256 + tid;
        const f4* p = (const f4*)(K + (size_t)i * 8);
        f4 a = p[0], b = p[1];
        bh8 w;
        #pragma unroll
        for (int k = 0; k < 4; ++k){ w[k] = (short)f2b(a[k]); w[k+4] = (short)f2b(b[k]); }
        *(bh8*)(Kb + (size_t)i * 8) = w;
    } else {                               // V transpose -> Vt[h][d][s] bf16 (+ column sums)
        __shared__ short T[64][72];
        __shared__ float red[64][4];
        const int r2 = bid - 2048;         // 0..1023 = head*32 + slice
        const int head = r2 >> 5;
        const int kv0  = (r2 & 31) * 64;
        {
            const int r = tid >> 2;
            const int s = (tid & 3) * 16;
            const float* vp = V + ((size_t)head * S_LEN + kv0 + r) * DHEAD + s;
            f4 v0 = *(const f4*)(vp);
            f4 v1 = *(const f4*)(vp + 4);
            f4 v2 = *(const f4*)(vp + 8);
            f4 v3 = *(const f4*)(vp + 12);
            float vv[16];
            *(f4*)&vv[0] = v0; *(f4*)&vv[4] = v1; *(f4*)&vv[8] = v2; *(f4*)&vv[12] = v3;
            #pragma unroll
            for (int i = 0; i < 16; ++i) T[r][s + i] = (short)f2b(vv[i]);
        }
        __syncthreads();
        {
            const int d  = tid >> 2;
            const int k0 = (tid & 3) * 16;
            bh8 w0, w1;
            float s16 = 0.f;
            #pragma unroll
            for (int i = 0; i < 8; ++i){
                w0[i] = T[k0 + i][d];
                w1[i] = T[k0 + 8 + i][d];
                s16 += b2f((ushort_t)w0[i]) + b2f((ushort_t)w1[i]);
            }
            ushort_t* op = Vt + ((size_t)head * DHEAD + d) * S_LEN + kv0 + k0;
            *(bh8*)op       = w0;
            *(bh8*)(op + 8) = w1;
            red[d][tid & 3] = s16;
        }
        __syncthreads();
        if (tid < 64)
            colpart[(size_t)r2 * 64 + tid] =
                red[tid][0] + red[tid][1] + red[tid][2] + red[tid][3];
    }
}

// ---- main attention: 1 q-tile/block, 4 waves split the KV range, LDS merge ----
__global__ __launch_bounds__(256, 4)
void attn_main(const float* __restrict__ Q, const ushort_t* __restrict__ Kb,
               const ushort_t* __restrict__ Vt, const int* __restrict__ M,
               float* __restrict__ Out)
{
    __shared__ char  Pl[4][2048];      // per-wave P buffer (loop phase)
    __shared__ float MG[2][32 * 64];   // merge slots, word-major (epilogue phase)
    __shared__ float MM[4][32], ML[4][32];

    const int tid  = threadIdx.x;
    const int wave = tid >> 6;
    const int lane = tid & 63;
    const int lq   = lane & 31;   // q column owned by this lane
    const int hi   = lane >> 5;

    const int bid  = blockIdx.x;
    // heads clustered per XCD (4 heads/XCD -> K+V L2-resident); jq descending (heaviest first)
    const int head = ((bid & 7) << 2) | ((bid >> 3) & 3);
    const int jq   = 63 - (bid >> 5);
    const int b    = head & (NBATCH - 1);
    const int q0   = jq << 5;
    const size_t hoff = (size_t)head * S_LEN * DHEAD;

    char* pw = Pl[wave] + lq * 64;              // this lane's P row (64 bytes)
    const int swzq = (lq ^ (lq >> 2)) & 3;      // 16B-block XOR swizzle per row

    // Q B-frags (col=lane&31=q, k=hi*8+j), scale 0.125*log2e folded in
    bh8 qB[4];
    {
        const float* qp = Q + hoff + (size_t)(q0 + lq) * DHEAD;
        const float qs = 0.125f * LOG2E;
        #pragma unroll
        for (int ks = 0; ks < 4; ++ks){
            f4 f0 = *(const f4*)(qp + ks * 16 + hi * 8);
            f4 f1 = *(const f4*)(qp + ks * 16 + hi * 8 + 4);
            bh8 a;
            #pragma unroll
            for (int i = 0; i < 4; ++i){
                a[i]   = (short)f2b(f0[i] * qs);
                a[i+4] = (short)f2b(f1[i] * qs);
            }
            qB[ks] = a;
        }
    }

    f16x acc0 = {};   // O^T rows d=0..31:  col=q=lq, row d=(reg&3)+8*(reg>>2)+4*hi
    f16x acc1 = {};   // O^T rows d=32..63
    float m = -INFINITY, l = 0.f;

    const ushort_t* kbase = Kb + hoff;
    const ushort_t* vbase = Vt + (size_t)head * DHEAD * S_LEN;
    const int* mrow = M + (size_t)b * S_LEN;

    // interleaved 4-way KV split: wave w handles kt = w, w+4, ...
    for (int kt = wave; kt <= jq; kt += 4){
        const int kv0 = kt << 5;
        // ---- all global loads issued up front ----
        bh8 kf[4], vf0[2], vf1[2];
        i4  mi[4];
        #pragma unroll
        for (int ks = 0; ks < 4; ++ks)
            kf[ks] = *(const bh8*)(kbase + (size_t)(kv0 + lq) * DHEAD + ks * 16 + hi * 8);
        #pragma unroll
        for (int kk = 0; kk < 2; ++kk){
            vf0[kk] = *(const bh8*)(vbase + (size_t)lq        * S_LEN + kv0 + kk * 16 + hi * 8);
            vf1[kk] = *(const bh8*)(vbase + (size_t)(32 + lq) * S_LEN + kv0 + kk * 16 + hi * 8);
        }
        #pragma unroll
        for (int g = 0; g < 4; ++g)
            mi[g] = *(const i4*)(mrow + kv0 + g * 8 + hi * 4);

        // ---- S^T = K Q^T (swapped): lane holds 16 scores of q-row lq ----
        f16x s = {};
        __builtin_amdgcn_s_setprio(1);
        #pragma unroll
        for (int ks = 0; ks < 4; ++ks)
            s = __builtin_amdgcn_mfma_f32_32x32x16_bf16(kf[ks], qB[ks], s, 0, 0, 0);
        __builtin_amdgcn_s_setprio(0);

        // ---- key-padding; causal on diagonal tile. reg g*4+i -> key 8g+4hi+i ----
        #pragma unroll
        for (int g = 0; g < 4; ++g)
            #pragma unroll
            for (int i = 0; i < 4; ++i)
                s[g * 4 + i] = (mi[g][i] != 0) ? CMASK : s[g * 4 + i];
        if (kt == jq){
            const int hb = hi << 2;
            #pragma unroll
            for (int g = 0; g < 4; ++g)
                #pragma unroll
                for (int i = 0; i < 4; ++i)
                    s[g * 4 + i] = (g * 8 + i + hb > lq) ? CMASK : s[g * 4 + i];
        }

        // ---- row max: local tree + shfl_xor across lane halves ----
        float t8[8];
        #pragma unroll
        for (int i = 0; i < 8; ++i) t8[i] = fmaxf(s[i], s[i + 8]);
        #pragma unroll
        for (int i = 0; i < 4; ++i) t8[i] = fmaxf(t8[i], t8[i + 4]);
        float pml = fmaxf(fmaxf(t8[0], t8[1]), fmaxf(t8[2], t8[3]));
        float pm  = fmaxf(pml, __shfl_xor(pml, 32, 64));

        // ---- deferred rescale (log2 units; 2^11 headroom is bf16/f32-safe) ----
        if (!__all(pm <= m + 11.0f)){
            float mn = fmaxf(m, pm);
            float al = __builtin_amdgcn_exp2f(m - mn);
            m = mn;
            l *= al;
            #pragma unroll
            for (int i = 0; i < 16; ++i){ acc0[i] *= al; acc1[i] *= al; }
        }

        // ---- P = exp2(S - m), row sum ----
        #pragma unroll
        for (int i = 0; i < 16; ++i) s[i] = __builtin_amdgcn_exp2f(s[i] - m);
        float u8[8];
        #pragma unroll
        for (int i = 0; i < 8; ++i) u8[i] = s[i] + s[i + 8];
        #pragma unroll
        for (int i = 0; i < 4; ++i) u8[i] = u8[i] + u8[i + 4];
        float lsl = (u8[0] + u8[1]) + (u8[2] + u8[3]);
        l += lsl + __shfl_xor(lsl, 32, 64);

        // ---- P -> LDS (C-layout) -> B-frag (per-wave buffer, no barrier) ----
        // physical 16B block of logical key k: (k>>3) ^ swzq ; reg g*4+i holds key 8g+4hi+i
        #pragma unroll
        for (int g = 0; g < 4; ++g){
            i2 w;
            w[0] = pack2(s[g * 4 + 0], s[g * 4 + 1]);
            w[1] = pack2(s[g * 4 + 2], s[g * 4 + 3]);
            *(i2*)(pw + (((g ^ swzq) << 4) + (hi << 3))) = w;
        }
        asm volatile("s_waitcnt lgkmcnt(0)" ::: "memory");
        __builtin_amdgcn_sched_barrier(0);
        bh8 pa1 = *(const bh8*)(pw + ((hi ^ swzq) << 4));          // keys hi*8+0..7
        bh8 pa2 = *(const bh8*)(pw + (((2 | hi) ^ swzq) << 4));    // keys 16+hi*8+0..7

        // ---- O^T += V^T P^T ----
        __builtin_amdgcn_s_setprio(1);
        acc0 = __builtin_amdgcn_mfma_f32_32x32x16_bf16(vf0[0], pa1, acc0, 0, 0, 0);
        acc0 = __builtin_amdgcn_mfma_f32_32x32x16_bf16(vf0[1], pa2, acc0, 0, 0, 0);
        acc1 = __builtin_amdgcn_mfma_f32_32x32x16_bf16(vf1[0], pa1, acc1, 0, 0, 0);
        acc1 = __builtin_amdgcn_mfma_f32_32x32x16_bf16(vf1[1], pa2, acc1, 0, 0, 0);
        __builtin_amdgcn_s_setprio(0);
    }

    // ---- 4-way (m,l,O) merge across waves ----
    if (hi == 0){ MM[wave][lq] = m; ML[wave][lq] = l; }
    __syncthreads();
    const float mstar = fmaxf(fmaxf(MM[0][lq], MM[1][lq]), fmaxf(MM[2][lq], MM[3][lq]));
    {
        const float aw = __builtin_amdgcn_exp2f(m - mstar);   // m = -inf (no work) -> 0
        #pragma unroll
        for (int i = 0; i < 16; ++i){ acc0[i] *= aw; acc1[i] *= aw; }
    }
    if (wave & 1){
        float* mg = MG[wave >> 1];
        #pragma unroll
        for (int i = 0; i < 16; ++i){
            mg[i * 64 + lane]        = acc0[i];
            mg[(16 + i) * 64 + lane] = acc1[i];
        }
    }
    __syncthreads();
    if (!(wave & 1)){
        const float* mg = MG[wave >> 1];
        #pragma unroll
        for (int i = 0; i < 16; ++i){
            acc0[i] += mg[i * 64 + lane];
            acc1[i] += mg[(16 + i) * 64 + lane];
        }
    }
    __syncthreads();
    if (wave == 2){
        float* mg = MG[0];
        #pragma unroll
        for (int i = 0; i < 16; ++i){
            mg[i * 64 + lane]        = acc0[i];
            mg[(16 + i) * 64 + lane] = acc1[i];
        }
    }
    __syncthreads();
    if (wave == 0){
        const float* mg = MG[0];
        #pragma unroll
        for (int i = 0; i < 16; ++i){
            acc0[i] += mg[i * 64 + lane];
            acc1[i] += mg[(16 + i) * 64 + lane];
        }
        float lstar = 0.f;
        #pragma unroll
        for (int w = 0; w < 4; ++w)
            lstar += __builtin_amdgcn_exp2f(MM[w][lq] - mstar) * ML[w][lq];
        const float inv = 1.0f / lstar;
        float* op = Out + hoff + (size_t)(q0 + lq) * DHEAD;
        #pragma unroll
        for (int g = 0; g < 4; ++g){
            f4 o0, o1;
            #pragma unroll
            for (int i = 0; i < 4; ++i){
                o0[i] = acc0[g * 4 + i] * inv;
                o1[i] = acc1[g * 4 + i] * inv;
            }
            *(f4*)(op + g * 8 + hi * 4)      = o0;
            *(f4*)(op + 32 + g * 8 + hi * 4) = o1;
        }
    }
}

// Rows q < q* (q* = first unmasked key of the batch): reference softmax is uniform over
// ALL 2048 keys -> output = column mean of V. Reduce prep's 32 partial sums per head.
__global__ __launch_bounds__(256)
void attn_fixup(const float* __restrict__ colpart, const int* __restrict__ M,
                float* __restrict__ Out)
{
    __shared__ float red[4][64];
    __shared__ int qstar;
    const int head = blockIdx.x;
    const int b = head & (NBATCH - 1);
    const int tid = threadIdx.x;
    const int col = tid & 63;
    const int grp = tid >> 6;
    {
        float s = 0.f;
        const float* cp = colpart + ((size_t)head * 32 + grp * 8) * 64 + col;
        #pragma unroll
        for (int j = 0; j < 8; ++j) s += cp[j * 64];
        red[grp][col] = s;
    }
    if (tid == 0){
        int q = 0;
        const int* mp = M + (size_t)b * S_LEN;
        while (q < S_LEN && mp[q]) ++q;
        qstar = q;
    }
    __syncthreads();
    const int qs = qstar;
    if (qs == 0) return;
    const float mean = (red[0][col] + red[1][col] + red[2][col] + red[3][col])
                       * (1.0f / S_LEN);
    for (int q = grp; q < qs; q += 4)
        Out[((size_t)head * S_LEN + q) * DHEAD + col] = mean;
}

extern "C" void kernel_launch(void* const* d_in, const int* in_sizes, int n_in,
                              void* d_out, int out_size, void* d_ws, size_t ws_size,
                              hipStream_t stream)
{
    const float* Q = (const float*)d_in[0];
    const float* K = (const float*)d_in[1];
    const float* V = (const float*)d_in[2];
    const int*   M = (const int*)d_in[3];
    float* Out = (float*)d_out;

    ushort_t* Kb = (ushort_t*)d_ws;                                  // 8.39 MB
    ushort_t* Vt = Kb + (size_t)NHEADS * S_LEN * DHEAD;              // 8.39 MB
    float* colpart = (float*)(Vt + (size_t)NHEADS * S_LEN * DHEAD);  // 256 KB

    prep      <<<dim3(3072),   dim3(256), 0, stream>>>(K, V, Kb, Vt, colpart);
    attn_main <<<dim3(2048),   dim3(256), 0, stream>>>(Q, Kb, Vt, M, Out);
    attn_fixup<<<dim3(NHEADS), dim3(256), 0, stream>>>(colpart, M, Out);
}